// Round 17
// baseline (44.156 us; speedup 1.0000x reference)
//
#include <hip/hip_runtime.h>
#include <hip/hip_bf16.h>

#define BB 8
#define NN 2048
#define FF 128

typedef __bf16 bf16x8 __attribute__((ext_vector_type(8)));
typedef float f32x4 __attribute__((ext_vector_type(4)));
typedef float f32x16 __attribute__((ext_vector_type(16)));

__device__ __forceinline__ void gload_lds16(const void* g, void* l) {
    __builtin_amdgcn_global_load_lds(
        (const __attribute__((address_space(1))) unsigned int*)g,
        (__attribute__((address_space(3))) unsigned int*)l, 16, 0, 0);
}

// ---------------------------------------------------------------------------
// Kernel A v13 (unchanged, refcheck-proven): W staged once to LDS as bf16
// transposed [c][k] -> B-frags via single ds_read_b128.
// ---------------------------------------------------------------------------
__global__ __launch_bounds__(256) void wh_kernel(
    const float* __restrict__ h, const float* __restrict__ W,
    const float* __restrict__ a, __bf16* __restrict__ fragB,
    float* __restrict__ srcg, float* __restrict__ dstg)
{
    __shared__ float  s_h[32][132];
    __shared__ __bf16 s_wh[32][132];
    __shared__ __bf16 s_Wt[128][136];
    __shared__ float  s_s[2][32];
    __shared__ float  s_d[2][32];

    const int bid = blockIdx.x;
    const int b   = bid >> 6;
    const int J   = bid & 63;
    const int r0  = J * 32;
    const int t   = threadIdx.x;
    const int w   = t >> 6;
    const int l   = t & 63;
    const int itile = w & 1;
    const int fh    = w >> 1;
    const int g     = l >> 4;
    const int c16   = l & 15;

#pragma unroll
    for (int i = 0; i < 4; ++i) {
        const int idx = t + i * 256;
        const int r   = idx >> 5;
        const int c4  = idx & 31;
        *(f32x4*)&s_h[r][c4 * 4] =
            *(const f32x4*)(h + (size_t)(b * NN + r0 + r) * FF + c4 * 4);
    }
    {
        const int wk  = t >> 1;
        const int wc0 = (t & 1) * 64;
        const float* wrow = W + wk * FF + wc0;
#pragma unroll
        for (int i = 0; i < 16; ++i) {
            const f32x4 v = *(const f32x4*)(wrow + i * 4);
            s_Wt[wc0 + i * 4 + 0][wk] = (__bf16)v[0];
            s_Wt[wc0 + i * 4 + 1][wk] = (__bf16)v[1];
            s_Wt[wc0 + i * 4 + 2][wk] = (__bf16)v[2];
            s_Wt[wc0 + i * 4 + 3][wk] = (__bf16)v[3];
        }
    }
    __syncthreads();

    const float* hrow = &s_h[itile * 16 + c16][0];
    f32x4 acc[4] = {};

#pragma unroll
    for (int kt = 0; kt < 4; ++kt) {
        const int k0 = kt * 32 + g * 8;
        f32x4 h0 = *(const f32x4*)(hrow + k0);
        f32x4 h1 = *(const f32x4*)(hrow + k0 + 4);
        bf16x8 af;
        af[0]=(__bf16)h0[0]; af[1]=(__bf16)h0[1]; af[2]=(__bf16)h0[2]; af[3]=(__bf16)h0[3];
        af[4]=(__bf16)h1[0]; af[5]=(__bf16)h1[1]; af[6]=(__bf16)h1[2]; af[7]=(__bf16)h1[3];
#pragma unroll
        for (int ft = 0; ft < 4; ++ft) {
            const int c = (fh * 4 + ft) * 16 + c16;
            const bf16x8 bf = *(const bf16x8*)&s_Wt[c][k0];
            acc[ft] = __builtin_amdgcn_mfma_f32_16x16x32_bf16(af, bf, acc[ft], 0, 0, 0);
        }
    }

    float a1v[4], a2v[4];
#pragma unroll
    for (int ft = 0; ft < 4; ++ft) {
        const int c = (fh * 4 + ft) * 16 + c16;
        a1v[ft] = a[c];
        a2v[ft] = a[FF + c];
    }
#pragma unroll
    for (int r = 0; r < 4; ++r) {
        float s = 0.f, d2 = 0.f;
#pragma unroll
        for (int ft = 0; ft < 4; ++ft) {
            s  += acc[ft][r] * a1v[ft];
            d2 += acc[ft][r] * a2v[ft];
        }
#pragma unroll
        for (int m = 1; m <= 8; m <<= 1) {
            s  += __shfl_xor(s,  m);
            d2 += __shfl_xor(d2, m);
        }
        if (c16 == 0) {
            s_s[fh][itile * 16 + g * 4 + r] = s;
            s_d[fh][itile * 16 + g * 4 + r] = d2;
        }
    }

#pragma unroll
    for (int ft = 0; ft < 4; ++ft)
#pragma unroll
        for (int r = 0; r < 4; ++r)
            s_wh[itile * 16 + g * 4 + r][(fh * 4 + ft) * 16 + c16] = (__bf16)acc[ft][r];

    __syncthreads();

#pragma unroll
    for (int e2 = 0; e2 < 2; ++e2) {
        const int ent  = t + e2 * 256;
        const int tile = ent >> 6;
        const int jl   = tile >> 2;
        const int ft   = tile & 3;
        const int lE   = ent & 63;
        const int rowE = jl * 16 + (lE >> 5) * 8;
        const int colE = ft * 32 + (lE & 31);
        bf16x8 v;
#pragma unroll
        for (int ee = 0; ee < 8; ++ee) v[ee] = s_wh[rowE + ee][colE];
        *(bf16x8*)(fragB + (((size_t)(b * 128 + J * 2 + jl) * 4 + ft) * 64 + lE) * 8) = v;
    }

    if (t < 32) {
        srcg[b * NN + r0 + t] = s_s[0][t] + s_s[1][t];
        dstg[b * NN + r0 + t] = s_d[0][t] + s_d[1][t];
    }
}

// ---------------------------------------------------------------------------
// Kernel B v16: STREAM-SPECIALIZED WAVES (stream-pure vmcnt queues).
// 32 steps x 64-j windows. Waves 0,1 issue ONLY frag DMA (8 x 1KB/step);
// waves 2,3 issue ONLY adj DMA (4 x 1KB/step each; contiguous 256-B row
// runs, chunk-XOR source swizzle) + dst prologue. ALL waves compute their
// K-quarter q from LDS after a per-step barrier (T3/T4 pattern).
//   frag: 3 slots x 16 KB, distance-1 (slot (w+1)%3 last read at step w-2:
//         WAR-safe since all waves passed barrier(w-1) before iter-w issue)
//   adj:  3 slots x 8 KB, distance-1 (same argument)
//   frag wave wait: vmcnt(8) retires F(w);  adj wave: vmcnt(4) retires A(w)
//   -> no wave's wait chain ever orders an L2 stream behind the HBM stream.
// Compute body / MFMA layout / combine / output: v8-verbatim (proven).
// LDS 80 KB exactly -> 2 blocks/CU.
// ---------------------------------------------------------------------------
__global__ __launch_bounds__(256, 2) void attn_kernel(
    const int* __restrict__ adj, const __bf16* __restrict__ fragB,
    const float* __restrict__ srcg, const float* __restrict__ dstg,
    float* __restrict__ out)
{
    __shared__ char s_all[81920];
    // [0,49152):      frag 3 slots x 16 KB  (slot s: s*16384 + op*1024 + l*16)
    // [49152,73728):  adj  3 slots x 8 KB   (slot s: op*1024 + l*16)
    // [73728,81920):  dst 8 KB (f32[2048]); first 512 B reused as s_ps after loop
    // tail combine reuses [0,69632)

    const int bid0 = blockIdx.x;
    const int bid  = (bid0 & 7) * 64 + (bid0 >> 3);   // bijective XCD swizzle
    const int b    = bid >> 6;
    const int I0   = (bid & 63) * 32;
    const int t    = threadIdx.x;
    const int q    = t >> 6;                  // wave = K-quarter (j-offset q*16)
    const int l    = t & 63;
    const int r31  = l & 31;
    const int hi   = l >> 5;

    float* dstf = (float*)(s_all + 73728);

    // ---- plain src load, fully drained BEFORE the DMA ledgers start ----
    const float sv = srcg[b * NN + I0 + r31];
    asm volatile("s_waitcnt vmcnt(0) lgkmcnt(0)" ::: "memory");

    // ---- frag-wave staging pointers (q < 2): ops o = q*8 + i ----
    const char* fragBB = (const char*)fragB + (size_t)b * 524288;
    const char* fSrc = fragBB + (size_t)(q & 1) * 8192 + (size_t)l * 16;
    const int   fDstL = (q & 1) * 8192 + l * 16;

    // ---- adj-wave staging pointers (q >= 2): ops o = (q-2)*4 + i ----
    const char* adjBB = (const char*)adj + (size_t)b * NN * (NN * 4);
    const int   o0   = (q & 1) * 4;          // (q-2)*4 for q in {2,3}
    const int   rl0  = o0 * 4 + (l >> 4);    // row of op i=0 for this lane
    const char* aS0 = adjBB + (size_t)(I0 + rl0)      * 8192 + (((l & 15) ^ ((rl0)      & 7)) * 16);
    const char* aS1 = adjBB + (size_t)(I0 + rl0 + 4)  * 8192 + (((l & 15) ^ ((rl0 + 4)  & 7)) * 16);
    const char* aS2 = adjBB + (size_t)(I0 + rl0 + 8)  * 8192 + (((l & 15) ^ ((rl0 + 8)  & 7)) * 16);
    const char* aS3 = adjBB + (size_t)(I0 + rl0 + 12) * 8192 + (((l & 15) ^ ((rl0 + 12) & 7)) * 16);
    const char* dS  = (const char*)(dstg + (size_t)b * NN) + o0 * 1024 + l * 16;

#define ISSUE_F(wc_, sl_) {                                                   \
        const char* ps_ = fSrc + (size_t)(wc_) * 16384;                       \
        char* pd_ = s_all + (sl_) * 16384 + fDstL;                            \
        _Pragma("unroll")                                                     \
        for (int i = 0; i < 8; ++i)                                           \
            gload_lds16(ps_ + i * 1024, pd_ + i * 1024);                      \
    }
#define ISSUE_A(wc_, sl_) {                                                   \
        const size_t wo_ = (size_t)(wc_) * 256;                               \
        char* pd_ = s_all + 49152 + (sl_) * 8192 + o0 * 1024 + l * 16;        \
        gload_lds16(aS0 + wo_, pd_);                                          \
        gload_lds16(aS1 + wo_, pd_ + 1024);                                   \
        gload_lds16(aS2 + wo_, pd_ + 2048);                                   \
        gload_lds16(aS3 + wo_, pd_ + 3072);                                   \
    }

    f32x16 acc0 = {}, acc1 = {}, acc2 = {}, acc3 = {};
    float psum = 0.f;

    // ---- prologue (stream-pure per wave) ----
    if (q < 2) {
        ISSUE_F(0, 0);                        // 8 outstanding
    } else {
        // dst: 4 ops (waves 2,3 together cover 8 KB)
        char* dd = (char*)dstf + o0 * 1024 + l * 16;
#pragma unroll
        for (int i = 0; i < 4; ++i)
            gload_lds16(dS + i * 1024, dd + i * 1024);
        ISSUE_A(0, 0);                        // dst(4) + A0(4) = 8 outstanding
    }

    const int c0 = q * 4 + hi * 2;
    const int x7 = r31 & 7;

    int scur = 0;
    for (int w = 0; w < 32; ++w) {
        const int snext = (scur == 2) ? 0 : scur + 1;
        const int wn = (w + 1 < 32) ? w + 1 : 31;   // clamped dummy keeps ledger
        if (q < 2) {
            ISSUE_F(wn, snext);
            // queue: F(w)[8] + F(w+1)[8] -> retire F(w)
            asm volatile("s_waitcnt vmcnt(8)" ::: "memory");
        } else {
            ISSUE_A(wn, snext);
            // queue: [dst+A(0) | A(w)][4-8] + A(w+1)[4] -> retire through A(w)
            asm volatile("s_waitcnt vmcnt(4)" ::: "memory");
        }
        __builtin_amdgcn_sched_barrier(0);
        __builtin_amdgcn_s_barrier();
        __builtin_amdgcn_sched_barrier(0);

        // ---- compute step w from slot scur (all waves) ----
        const char* asl = s_all + 49152 + scur * 8192
                        + (r31 >> 2) * 1024 + (r31 & 3) * 256;
        const int4 A0 = *(const int4*)(asl + ((c0       ^ x7) * 16));
        const int4 A1 = *(const int4*)(asl + (((c0 + 1) ^ x7) * 16));
        const float* dw = dstf + w * 64 + q * 16 + hi * 8;
        const f32x4 d0 = *(const f32x4*)(dw);
        const f32x4 d1 = *(const f32x4*)(dw + 4);
        const int   am[8] = {A0.x, A0.y, A0.z, A0.w, A1.x, A1.y, A1.z, A1.w};
        const float dv[8] = {d0[0], d0[1], d0[2], d0[3], d1[0], d1[1], d1[2], d1[3]};

        bf16x8 af;
#pragma unroll
        for (int e = 0; e < 8; ++e) {
            float x = sv + dv[e];
            x = fmaxf(x, 0.2f * x);          // leaky_relu 0.2
            float p = __expf(x);             // bounded, no max-sub needed
            p = (am[e] > 0) ? p : 0.f;
            psum += p;
            af[e] = (__bf16)p;
        }

        const char* fsl = s_all + scur * 16384 + q * 4096 + l * 16;
        const bf16x8 b0 = *(const bf16x8*)(fsl);
        const bf16x8 b1 = *(const bf16x8*)(fsl + 1024);
        const bf16x8 b2 = *(const bf16x8*)(fsl + 2048);
        const bf16x8 b3 = *(const bf16x8*)(fsl + 3072);
        acc0 = __builtin_amdgcn_mfma_f32_32x32x16_bf16(af, b0, acc0, 0, 0, 0);
        acc1 = __builtin_amdgcn_mfma_f32_32x32x16_bf16(af, b1, acc1, 0, 0, 0);
        acc2 = __builtin_amdgcn_mfma_f32_32x32x16_bf16(af, b2, acc2, 0, 0, 0);
        acc3 = __builtin_amdgcn_mfma_f32_32x32x16_bf16(af, b3, acc3, 0, 0, 0);

        scur = snext;
    }
#undef ISSUE_F
#undef ISSUE_A

    asm volatile("s_waitcnt vmcnt(0) lgkmcnt(0)" ::: "memory");  // drain dummies

    // denom partial: lanes l and l^32 cover the same row, disjoint j
    psum += __shfl_xor(psum, 32);

    __syncthreads();                          // all waves done with K-loop/dst
    float* s_ps = (float*)(s_all + 73728);    // reuse dst region
    if (l < 32) s_ps[q * 32 + l] = psum;

    // ---- 4-way j-partial combine (reuse pipe LDS: [4 q][4 ft][64][17]) ----
    float* comb = (float*)s_all;
    {
        float* cb = comb + ((q * 4 + 0) * 64 + l) * 17;
#pragma unroll
        for (int r = 0; r < 16; ++r) cb[r] = acc0[r];
        cb = comb + ((q * 4 + 1) * 64 + l) * 17;
#pragma unroll
        for (int r = 0; r < 16; ++r) cb[r] = acc1[r];
        cb = comb + ((q * 4 + 2) * 64 + l) * 17;
#pragma unroll
        for (int r = 0; r < 16; ++r) cb[r] = acc2[r];
        cb = comb + ((q * 4 + 3) * 64 + l) * 17;
#pragma unroll
        for (int r = 0; r < 16; ++r) cb[r] = acc3[r];
    }
    __syncthreads();

    // wave q owns output ft-tile q
    f32x16 tot;
#pragma unroll
    for (int r = 0; r < 16; ++r)
        tot[r] = comb[((0 * 4 + q) * 64 + l) * 17 + r]
               + comb[((1 * 4 + q) * 64 + l) * 17 + r]
               + comb[((2 * 4 + q) * 64 + l) * 17 + r]
               + comb[((3 * 4 + q) * 64 + l) * 17 + r];

    const float dtot = s_ps[0 * 32 + r31] + s_ps[1 * 32 + r31]
                     + s_ps[2 * 32 + r31] + s_ps[3 * 32 + r31];
    const float rin  = 1.f / dtot;

    // C layout (32x32): col = l&31, row = (r&3) + 8*(r>>2) + 4*hi
#pragma unroll
    for (int r = 0; r < 16; ++r) {
        const int row  = (r & 3) + 8 * (r >> 2) + 4 * hi;
        const float dv2 = __shfl(rin, row);
        out[(size_t)(b * NN + I0 + row) * FF + q * 32 + r31] = tot[r] * dv2;
    }
}

// ---------------------------------------------------------------------------
extern "C" void kernel_launch(void* const* d_in, const int* in_sizes, int n_in,
                              void* d_out, int out_size, void* d_ws, size_t ws_size,
                              hipStream_t stream)
{
    const float* h   = (const float*)d_in[0];
    const int*   adj = (const int*)d_in[1];
    const float* W   = (const float*)d_in[2];
    const float* a   = (const float*)d_in[3];
    float* out = (float*)d_out;

    char* ws = (char*)d_ws;
    __bf16* fragB = (__bf16*)ws;                              // 4 MiB
    float*  srcg  = (float*)(ws + (4 << 20));                 // 64 KiB
    float*  dstg  = (float*)(ws + (4 << 20) + (64 << 10));    // 64 KiB

    wh_kernel<<<512, 256, 0, stream>>>(h, W, a, fragB, srcg, dstg);
    attn_kernel<<<512, 256, 0, stream>>>(adj, fragB, srcg, dstg, out);
}

// Round 18
// 39.649 us; speedup vs baseline: 1.1137x; 1.1137x over previous
//
#include <hip/hip_runtime.h>
#include <hip/hip_bf16.h>

#define BB 8
#define NN 2048
#define FF 128

typedef __bf16 bf16x8 __attribute__((ext_vector_type(8)));
typedef float f32x4 __attribute__((ext_vector_type(4)));
typedef float f32x16 __attribute__((ext_vector_type(16)));

__device__ __forceinline__ void gload_lds16(const void* g, void* l) {
    __builtin_amdgcn_global_load_lds(
        (const __attribute__((address_space(1))) unsigned int*)g,
        (__attribute__((address_space(3))) unsigned int*)l, 16, 0, 0);
}

// ---------------------------------------------------------------------------
// Kernel A v14: 256 blocks x 2 J-tiles (W staged to LDS ONCE per block,
// halving the redundant W re-read traffic; h/wh buffers reused across the
// tile loop). Inner per-tile code is v13-verbatim (refcheck-proven).
// ---------------------------------------------------------------------------
__global__ __launch_bounds__(256) void wh_kernel(
    const float* __restrict__ h, const float* __restrict__ W,
    const float* __restrict__ a, __bf16* __restrict__ fragB,
    float* __restrict__ srcg, float* __restrict__ dstg)
{
    __shared__ float  s_h[32][132];
    __shared__ __bf16 s_wh[32][132];
    __shared__ __bf16 s_Wt[128][136];
    __shared__ float  s_s[2][32];
    __shared__ float  s_d[2][32];

    const int bid = blockIdx.x;            // 256 blocks: b = bid>>5, Jpair = bid&31
    const int b   = bid >> 5;
    const int t   = threadIdx.x;
    const int w   = t >> 6;
    const int l   = t & 63;
    const int itile = w & 1;
    const int fh    = w >> 1;
    const int g     = l >> 4;
    const int c16   = l & 15;

    // W -> LDS transposed bf16, once per block
    {
        const int wk  = t >> 1;
        const int wc0 = (t & 1) * 64;
        const float* wrow = W + wk * FF + wc0;
#pragma unroll
        for (int i = 0; i < 16; ++i) {
            const f32x4 v = *(const f32x4*)(wrow + i * 4);
            s_Wt[wc0 + i * 4 + 0][wk] = (__bf16)v[0];
            s_Wt[wc0 + i * 4 + 1][wk] = (__bf16)v[1];
            s_Wt[wc0 + i * 4 + 2][wk] = (__bf16)v[2];
            s_Wt[wc0 + i * 4 + 3][wk] = (__bf16)v[3];
        }
    }

    float a1v[4], a2v[4];
#pragma unroll
    for (int ft = 0; ft < 4; ++ft) {
        const int c = (fh * 4 + ft) * 16 + c16;
        a1v[ft] = a[c];
        a2v[ft] = a[FF + c];
    }

    for (int jt2 = 0; jt2 < 2; ++jt2) {
        const int J  = (bid & 31) * 2 + jt2;
        const int r0 = J * 32;

        __syncthreads();   // W ready (iter 0); s_h/s_wh readers done (iter 1)

#pragma unroll
        for (int i = 0; i < 4; ++i) {
            const int idx = t + i * 256;
            const int r   = idx >> 5;
            const int c4  = idx & 31;
            *(f32x4*)&s_h[r][c4 * 4] =
                *(const f32x4*)(h + (size_t)(b * NN + r0 + r) * FF + c4 * 4);
        }
        __syncthreads();

        const float* hrow = &s_h[itile * 16 + c16][0];
        f32x4 acc[4] = {};

#pragma unroll
        for (int kt = 0; kt < 4; ++kt) {
            const int k0 = kt * 32 + g * 8;
            f32x4 h0 = *(const f32x4*)(hrow + k0);
            f32x4 h1 = *(const f32x4*)(hrow + k0 + 4);
            bf16x8 af;
            af[0]=(__bf16)h0[0]; af[1]=(__bf16)h0[1]; af[2]=(__bf16)h0[2]; af[3]=(__bf16)h0[3];
            af[4]=(__bf16)h1[0]; af[5]=(__bf16)h1[1]; af[6]=(__bf16)h1[2]; af[7]=(__bf16)h1[3];
#pragma unroll
            for (int ft = 0; ft < 4; ++ft) {
                const int c = (fh * 4 + ft) * 16 + c16;
                const bf16x8 bf = *(const bf16x8*)&s_Wt[c][k0];
                acc[ft] = __builtin_amdgcn_mfma_f32_16x16x32_bf16(af, bf, acc[ft], 0, 0, 0);
            }
        }

#pragma unroll
        for (int r = 0; r < 4; ++r) {
            float s = 0.f, d2 = 0.f;
#pragma unroll
            for (int ft = 0; ft < 4; ++ft) {
                s  += acc[ft][r] * a1v[ft];
                d2 += acc[ft][r] * a2v[ft];
            }
#pragma unroll
            for (int m = 1; m <= 8; m <<= 1) {
                s  += __shfl_xor(s,  m);
                d2 += __shfl_xor(d2, m);
            }
            if (c16 == 0) {
                s_s[fh][itile * 16 + g * 4 + r] = s;
                s_d[fh][itile * 16 + g * 4 + r] = d2;
            }
        }

#pragma unroll
        for (int ft = 0; ft < 4; ++ft)
#pragma unroll
            for (int r = 0; r < 4; ++r)
                s_wh[itile * 16 + g * 4 + r][(fh * 4 + ft) * 16 + c16] = (__bf16)acc[ft][r];

        __syncthreads();

#pragma unroll
        for (int e2 = 0; e2 < 2; ++e2) {
            const int ent  = t + e2 * 256;
            const int tile = ent >> 6;
            const int jl   = tile >> 2;
            const int ft   = tile & 3;
            const int lE   = ent & 63;
            const int rowE = jl * 16 + (lE >> 5) * 8;
            const int colE = ft * 32 + (lE & 31);
            bf16x8 v;
#pragma unroll
            for (int ee = 0; ee < 8; ++ee) v[ee] = s_wh[rowE + ee][colE];
            *(bf16x8*)(fragB + (((size_t)(b * 128 + J * 2 + jl) * 4 + ft) * 64 + lE) * 8) = v;
        }

        if (t < 32) {
            srcg[b * NN + r0 + t] = s_s[0][t] + s_s[1][t];
            dstg[b * NN + r0 + t] = s_d[0][t] + s_d[1][t];
        }
    }
}

// ---------------------------------------------------------------------------
// Kernel B v13 (byte-identical — best passing version, 39.8 us total):
// contiguous adj staging [32 rows][512B]/step, depth-4 slots, per-step
// {vmcnt(12); sched_barrier; s_barrier}; frag = asm reg loads distance-1.
// adj stream measured at HBM wire speed (NOFRAG 21.6 us) — rate-limited.
// ---------------------------------------------------------------------------
__global__ __launch_bounds__(256, 2) void attn_kernel(
    const int* __restrict__ adj, const __bf16* __restrict__ fragB,
    const float* __restrict__ srcg, const float* __restrict__ dstg,
    float* __restrict__ out)
{
    __shared__ char s_all[74240];

    const int bid0 = blockIdx.x;
    const int bid  = (bid0 & 7) * 64 + (bid0 >> 3);   // bijective XCD swizzle
    const int b    = bid >> 6;
    const int I0   = (bid & 63) * 32;
    const int t    = threadIdx.x;
    const int q    = t >> 6;
    const int l    = t & 63;
    const int r31  = l & 31;
    const int hi   = l >> 5;
    const int xr   = l & 7;

    float* dstf = (float*)(s_all + 65536);
    float* s_ps = (float*)(s_all + 73728);

    const float sv = srcg[b * NN + I0 + r31];
    asm volatile("s_waitcnt vmcnt(0) lgkmcnt(0)" ::: "memory");

    const char* adjBB = (const char*)adj + (size_t)b * NN * (NN * 4);
    const int ro0 = 2 * (q * 4 + 0) + hi;
    const int ro1 = 2 * (q * 4 + 1) + hi;
    const int ro2 = 2 * (q * 4 + 2) + hi;
    const int ro3 = 2 * (q * 4 + 3) + hi;
    const char* aB0 = adjBB + (size_t)(I0 + ro0) * (NN * 4) + ((r31 ^ (ro0 & 7)) * 16);
    const char* aB1 = adjBB + (size_t)(I0 + ro1) * (NN * 4) + ((r31 ^ (ro1 & 7)) * 16);
    const char* aB2 = adjBB + (size_t)(I0 + ro2) * (NN * 4) + ((r31 ^ (ro2 & 7)) * 16);
    const char* aB3 = adjBB + (size_t)(I0 + ro3) * (NN * 4) + ((r31 ^ (ro3 & 7)) * 16);
    const char* fB = (const char*)fragB + ((size_t)(b * 128 + q * 2) * 4096)
                     + (size_t)l * 16;
    const char* dS = (const char*)(dstg + (size_t)b * NN) + q * 2048 + l * 16;

#define ISSUE_A(w_, sl_) {                                                    \
        const size_t wo_ = (size_t)(w_) * 512;                                \
        char* ds_ = s_all + (sl_) * 16384 + q * 4096 + l * 16;                \
        gload_lds16(aB0 + wo_, ds_);                                          \
        gload_lds16(aB1 + wo_, ds_ + 1024);                                   \
        gload_lds16(aB2 + wo_, ds_ + 2048);                                   \
        gload_lds16(aB3 + wo_, ds_ + 3072); }

#define ISSUE_F(w_, B0_,B1_,B2_,B3_,B4_,B5_,B6_,B7_) {                        \
        const int wc_ = ((w_) < 16) ? (w_) : 15;                              \
        const char* p0_ = fB + (size_t)wc_ * 32768;                           \
        const char* p1_ = p0_ + 4096;                                         \
        asm volatile("global_load_dwordx4 %0, %1, off"                        \
                     : "=&v"(B0_) : "v"(p0_));                                \
        asm volatile("global_load_dwordx4 %0, %1, off offset:1024"            \
                     : "=&v"(B1_) : "v"(p0_));                                \
        asm volatile("global_load_dwordx4 %0, %1, off offset:2048"            \
                     : "=&v"(B2_) : "v"(p0_));                                \
        asm volatile("global_load_dwordx4 %0, %1, off offset:3072"            \
                     : "=&v"(B3_) : "v"(p0_));                                \
        asm volatile("global_load_dwordx4 %0, %1, off"                        \
                     : "=&v"(B4_) : "v"(p1_));                                \
        asm volatile("global_load_dwordx4 %0, %1, off offset:1024"            \
                     : "=&v"(B5_) : "v"(p1_));                                \
        asm volatile("global_load_dwordx4 %0, %1, off offset:2048"            \
                     : "=&v"(B6_) : "v"(p1_));                                \
        asm volatile("global_load_dwordx4 %0, %1, off offset:3072"            \
                     : "=&v"(B7_) : "v"(p1_)); }

    bf16x8 Fa0, Fa1, Fa2, Fa3, Fa4, Fa5, Fa6, Fa7;
    bf16x8 Fb0, Fb1, Fb2, Fb3, Fb4, Fb5, Fb6, Fb7;
    f32x16 acc0 = {}, acc1 = {}, acc2 = {}, acc3 = {};
    float psum = 0.f;

    gload_lds16(dS,        (char*)dstf + q * 2048 + l * 16);
    gload_lds16(dS + 1024, (char*)dstf + q * 2048 + 1024 + l * 16);
    ISSUE_A(0, 0);
    ISSUE_F(0, Fa0, Fa1, Fa2, Fa3, Fa4, Fa5, Fa6, Fa7);

#define STEP(w_, C0_,C1_,C2_,C3_,C4_,C5_,C6_,C7_, N0_,N1_,N2_,N3_,N4_,N5_,N6_,N7_) { \
        const int wn_ = ((w_) + 1 < 16) ? (w_) + 1 : 15;                      \
        ISSUE_F(wn_, N0_, N1_, N2_, N3_, N4_, N5_, N6_, N7_);                 \
        ISSUE_A(wn_, wn_ & 3);                                                \
        asm volatile("s_waitcnt vmcnt(12)" ::: "memory");                     \
        __builtin_amdgcn_sched_barrier(0);                                    \
        __builtin_amdgcn_s_barrier();                                         \
        const char* as_ = s_all + ((w_) & 3) * 16384 + r31 * 512;             \
        const int cqa_ = q * 8 + hi * 2;                                      \
        const int cqb_ = cqa_ + 4;                                            \
        const int4 A00_ = *(const int4*)(as_ + ((cqa_ ^ xr) * 16));           \
        const int4 A01_ = *(const int4*)(as_ + (((cqa_ + 1) ^ xr) * 16));     \
        const int4 A10_ = *(const int4*)(as_ + ((cqb_ ^ xr) * 16));           \
        const int4 A11_ = *(const int4*)(as_ + (((cqb_ + 1) ^ xr) * 16));     \
        const float* dw_ = dstf + (w_) * 128 + q * 32 + hi * 8;               \
        const f32x4 d00_ = *(const f32x4*)(dw_);                              \
        const f32x4 d01_ = *(const f32x4*)(dw_ + 4);                          \
        const f32x4 d10_ = *(const f32x4*)(dw_ + 16);                         \
        const f32x4 d11_ = *(const f32x4*)(dw_ + 20);                         \
        const int   am0_[8] = {A00_.x, A00_.y, A00_.z, A00_.w,                \
                               A01_.x, A01_.y, A01_.z, A01_.w};               \
        const int   am1_[8] = {A10_.x, A10_.y, A10_.z, A10_.w,                \
                               A11_.x, A11_.y, A11_.z, A11_.w};               \
        const float dv0_[8] = {d00_[0], d00_[1], d00_[2], d00_[3],            \
                               d01_[0], d01_[1], d01_[2], d01_[3]};           \
        const float dv1_[8] = {d10_[0], d10_[1], d10_[2], d10_[3],            \
                               d11_[0], d11_[1], d11_[2], d11_[3]};           \
        bf16x8 af0_, af1_;                                                    \
        _Pragma("unroll")                                                     \
        for (int e = 0; e < 8; ++e) {                                         \
            float x0 = sv + dv0_[e];                                          \
            x0 = fmaxf(x0, 0.2f * x0);                                        \
            float p0 = __expf(x0);                                            \
            p0 = (am0_[e] > 0) ? p0 : 0.f;                                    \
            psum += p0;                                                       \
            af0_[e] = (__bf16)p0;                                             \
            float x1 = sv + dv1_[e];                                          \
            x1 = fmaxf(x1, 0.2f * x1);                                        \
            float p1 = __expf(x1);                                            \
            p1 = (am1_[e] > 0) ? p1 : 0.f;                                    \
            psum += p1;                                                       \
            af1_[e] = (__bf16)p1;                                             \
        }                                                                     \
        acc0 = __builtin_amdgcn_mfma_f32_32x32x16_bf16(af0_, C0_, acc0, 0, 0, 0); \
        acc1 = __builtin_amdgcn_mfma_f32_32x32x16_bf16(af0_, C1_, acc1, 0, 0, 0); \
        acc2 = __builtin_amdgcn_mfma_f32_32x32x16_bf16(af0_, C2_, acc2, 0, 0, 0); \
        acc3 = __builtin_amdgcn_mfma_f32_32x32x16_bf16(af0_, C3_, acc3, 0, 0, 0); \
        acc0 = __builtin_amdgcn_mfma_f32_32x32x16_bf16(af1_, C4_, acc0, 0, 0, 0); \
        acc1 = __builtin_amdgcn_mfma_f32_32x32x16_bf16(af1_, C5_, acc1, 0, 0, 0); \
        acc2 = __builtin_amdgcn_mfma_f32_32x32x16_bf16(af1_, C6_, acc2, 0, 0, 0); \
        acc3 = __builtin_amdgcn_mfma_f32_32x32x16_bf16(af1_, C7_, acc3, 0, 0, 0); }

    for (int w2 = 0; w2 < 16; w2 += 2) {
        STEP(w2 + 0, Fa0,Fa1,Fa2,Fa3,Fa4,Fa5,Fa6,Fa7,
                     Fb0,Fb1,Fb2,Fb3,Fb4,Fb5,Fb6,Fb7);
        STEP(w2 + 1, Fb0,Fb1,Fb2,Fb3,Fb4,Fb5,Fb6,Fb7,
                     Fa0,Fa1,Fa2,Fa3,Fa4,Fa5,Fa6,Fa7);
    }
#undef STEP
#undef ISSUE_A
#undef ISSUE_F

    asm volatile("s_waitcnt vmcnt(0) lgkmcnt(0)" ::: "memory");

    psum += __shfl_xor(psum, 32);
    if (l < 32) s_ps[q * 32 + l] = psum;

    float* comb = (float*)s_all;
    f32x16 tot;

    __syncthreads();
    {
        float* c0 = comb + ((q * 2 + 0) * 64 + l) * 17;
        float* c1 = comb + ((q * 2 + 1) * 64 + l) * 17;
#pragma unroll
        for (int r = 0; r < 16; ++r) { c0[r] = acc0[r]; c1[r] = acc1[r]; }
    }
    __syncthreads();
    if (q < 2) {
#pragma unroll
        for (int r = 0; r < 16; ++r)
            tot[r] = comb[((0 * 2 + q) * 64 + l) * 17 + r]
                   + comb[((1 * 2 + q) * 64 + l) * 17 + r]
                   + comb[((2 * 2 + q) * 64 + l) * 17 + r]
                   + comb[((3 * 2 + q) * 64 + l) * 17 + r];
    }
    __syncthreads();
    {
        float* c0 = comb + ((q * 2 + 0) * 64 + l) * 17;
        float* c1 = comb + ((q * 2 + 1) * 64 + l) * 17;
#pragma unroll
        for (int r = 0; r < 16; ++r) { c0[r] = acc2[r]; c1[r] = acc3[r]; }
    }
    __syncthreads();
    if (q >= 2) {
        const int f2 = q - 2;
#pragma unroll
        for (int r = 0; r < 16; ++r)
            tot[r] = comb[((0 * 2 + f2) * 64 + l) * 17 + r]
                   + comb[((1 * 2 + f2) * 64 + l) * 17 + r]
                   + comb[((2 * 2 + f2) * 64 + l) * 17 + r]
                   + comb[((3 * 2 + f2) * 64 + l) * 17 + r];
    }

    const float dtot = s_ps[0 * 32 + r31] + s_ps[1 * 32 + r31]
                     + s_ps[2 * 32 + r31] + s_ps[3 * 32 + r31];
    const float rin  = 1.f / dtot;

#pragma unroll
    for (int r = 0; r < 16; ++r) {
        const int row  = (r & 3) + 8 * (r >> 2) + 4 * hi;
        const float dv2 = __shfl(rin, row);
        out[(size_t)(b * NN + I0 + row) * FF + q * 32 + r31] = tot[r] * dv2;
    }
}

// ---------------------------------------------------------------------------
extern "C" void kernel_launch(void* const* d_in, const int* in_sizes, int n_in,
                              void* d_out, int out_size, void* d_ws, size_t ws_size,
                              hipStream_t stream)
{
    const float* h   = (const float*)d_in[0];
    const int*   adj = (const int*)d_in[1];
    const float* W   = (const float*)d_in[2];
    const float* a   = (const float*)d_in[3];
    float* out = (float*)d_out;

    char* ws = (char*)d_ws;
    __bf16* fragB = (__bf16*)ws;                              // 4 MiB
    float*  srcg  = (float*)(ws + (4 << 20));                 // 64 KiB
    float*  dstg  = (float*)(ws + (4 << 20) + (64 << 10));    // 64 KiB

    wh_kernel<<<256, 256, 0, stream>>>(h, W, a, fragB, srcg, dstg);
    attn_kernel<<<512, 256, 0, stream>>>(adj, fragB, srcg, dstg, out);
}